// Round 1
// baseline (855.244 us; speedup 1.0000x reference)
//
#include <hip/hip_runtime.h>

#define BB 8
#define TT 12
#define NN 10000
#define HH 32
#define EE 320000
#define HOR 12

static __device__ __forceinline__ float sigm(float x) { return 1.0f/(1.0f+__expf(-x)); }
static __device__ __forceinline__ float tanh_fast(float x) { return 1.0f - 2.0f/(1.0f+__expf(2.0f*x)); }

// ---- tiny precompute: A[96] = enc_w . w_ih^T ; W2[160x12] = filt_w @ dec_w ; b2[12]
__global__ void k_prep(const float* __restrict__ enc_w, const float* __restrict__ w_ih,
                       const float* __restrict__ filt_w, const float* __restrict__ filt_b,
                       const float* __restrict__ dec_w, const float* __restrict__ dec_b,
                       float* __restrict__ A, float* __restrict__ W2, float* __restrict__ b2) {
    for (int i = threadIdx.x; i < 96 + 160*12 + 12; i += blockDim.x) {
        if (i < 96) {
            float s = 0.f;
            for (int h = 0; h < HH; h++) s += enc_w[h] * w_ih[i*HH + h];
            A[i] = s;
        } else if (i < 96 + 1920) {
            int j = i - 96; int c = j / 12, o = j % 12;
            float s = 0.f;
            for (int h = 0; h < HH; h++) s += filt_w[c*HH + h] * dec_w[h*12 + o];
            W2[j] = s;
        } else {
            int o = i - 2016;
            float s = dec_b[o];
            for (int h = 0; h < HH; h++) s += filt_b[h] * dec_w[h*12 + o];
            b2[o] = s;
        }
    }
}

// ---- CB[n][96] = b_ih[g] + sum_h (enc_b[h]+node_emb[n,h]) * w_ih[g,h]
__global__ void k_cb(const float* __restrict__ node_emb, const float* __restrict__ enc_b,
                     const float* __restrict__ w_ih, const float* __restrict__ b_ih,
                     float* __restrict__ CB) {
    int id = blockIdx.x * blockDim.x + threadIdx.x;  // N*96 exactly
    int n = id / 96, g = id % 96;
    float s = b_ih[g];
    const float* ne = node_emb + (size_t)n * HH;
    #pragma unroll
    for (int h = 0; h < HH; h++) s += (enc_b[h] + ne[h]) * w_ih[g*HH + h];
    CB[id] = s;
}

// ---- histogram of edge endpoints + weighted degrees
__global__ void k_hist(const int* __restrict__ ei, const float* __restrict__ ew,
                       int* cnt_f, int* cnt_b, float* deg_f, float* deg_b) {
    int e = blockIdx.x * blockDim.x + threadIdx.x;  // EE exactly
    int s = ei[e], t = ei[EE + e];
    float w = ew[e];
    atomicAdd(&cnt_f[t], 1); atomicAdd(&deg_f[t], w);
    atomicAdd(&cnt_b[s], 1); atomicAdd(&deg_b[s], w);
}

// ---- single-block exclusive scan (2 blocks: fwd / bwd) + inv-degree
__global__ void k_scan(const int* __restrict__ cnt_f, const float* __restrict__ deg_f,
                       int* off_f, int* cur_f, float* inv_f,
                       const int* __restrict__ cnt_b, const float* __restrict__ deg_b,
                       int* off_b, int* cur_b, float* inv_b) {
    const int* cnt; const float* deg; int* off; int* cur; float* inv;
    if (blockIdx.x == 0) { cnt = cnt_f; deg = deg_f; off = off_f; cur = cur_f; inv = inv_f; }
    else                 { cnt = cnt_b; deg = deg_b; off = off_b; cur = cur_b; inv = inv_b; }
    __shared__ int part[1024];
    int t = threadIdx.x;
    const int CH = (NN + 1023) / 1024;  // 10
    int beg = t * CH, end = min(beg + CH, NN);
    int s = 0;
    for (int i = beg; i < end; i++) s += cnt[i];
    part[t] = s;
    __syncthreads();
    for (int d = 1; d < 1024; d <<= 1) {
        int add = (t >= d) ? part[t - d] : 0;
        __syncthreads();
        part[t] += add;
        __syncthreads();
    }
    int run = part[t] - s;  // exclusive base
    for (int i = beg; i < end; i++) {
        off[i] = run; cur[i] = run; run += cnt[i];
        float dv = deg[i];
        inv[i] = dv > 0.f ? 1.0f / dv : 1.0f;
    }
    if (t == 1023) off[NN] = part[1023];
}

// ---- scatter edges into CSR buckets
__global__ void k_fill(const int* __restrict__ ei, const float* __restrict__ ew,
                       int* cur_f, int* csr_f_idx, float* csr_f_w,
                       int* cur_b, int* csr_b_idx, float* csr_b_w) {
    int e = blockIdx.x * blockDim.x + threadIdx.x;  // EE exactly
    int s = ei[e], t = ei[EE + e]; float w = ew[e];
    int pf = atomicAdd(&cur_f[t], 1); csr_f_idx[pf] = s; csr_f_w[pf] = w;
    int pb = atomicAdd(&cur_b[s], 1); csr_b_idx[pb] = t; csr_b_w[pb] = w;
}

// ---- fused GRU over T=12; one thread per (b,n) row; h in registers
__global__ __launch_bounds__(320) void k_gru(const float* __restrict__ x,
                      const float* __restrict__ CB, const float* __restrict__ A,
                      const float* __restrict__ w_hh, const float* __restrict__ b_hh,
                      float* __restrict__ hout) {
    int r = blockIdx.x * blockDim.x + threadIdx.x;  // 80000 exactly
    int b = r / NN, n = r % NN;
    float cb[96];
    const float4* c4 = (const float4*)(CB + (size_t)n * 96);
    #pragma unroll
    for (int q = 0; q < 24; q++) {
        float4 v = c4[q];
        cb[4*q] = v.x; cb[4*q+1] = v.y; cb[4*q+2] = v.z; cb[4*q+3] = v.w;
    }
    float hid[HH];
    #pragma unroll
    for (int i = 0; i < HH; i++) hid[i] = 0.f;
    const float* xp = x + (size_t)b * TT * NN + n;
    #pragma unroll 1
    for (int t = 0; t < TT; t++) {
        float xv = xp[(size_t)t * NN];
        float nh[HH];
        #pragma unroll 8
        for (int j = 0; j < HH; j++) {
            float gr = b_hh[j], gz = b_hh[HH + j], gn = b_hh[2*HH + j];
            #pragma unroll
            for (int h = 0; h < HH; h++) {
                float hv = hid[h];
                gr += hv * w_hh[j*HH + h];
                gz += hv * w_hh[(HH + j)*HH + h];
                gn += hv * w_hh[(2*HH + j)*HH + h];
            }
            float rr = sigm(xv * A[j]        + cb[j]        + gr);
            float zz = sigm(xv * A[HH + j]   + cb[HH + j]   + gz);
            float nn = tanh_fast(xv * A[2*HH + j] + cb[2*HH + j] + rr * gn);
            nh[j] = (1.f - zz) * nn + zz * hid[j];
        }
        #pragma unroll
        for (int j = 0; j < HH; j++) hid[j] = nh[j];
    }
    float4* o = (float4*)(hout + (size_t)r * HH);
    #pragma unroll
    for (int q = 0; q < 8; q++) {
        float4 v; v.x = hid[4*q]; v.y = hid[4*q+1]; v.z = hid[4*q+2]; v.w = hid[4*q+3];
        o[q] = v;
    }
}

// ---- one diffusion hop: y[b,n,:] = inv_deg[n] * sum_e w[e]*x[b,idx[e],:]
__global__ void k_prop(const float* __restrict__ xin, float* __restrict__ yout,
                       const int* __restrict__ off, const int* __restrict__ idx,
                       const float* __restrict__ w, const float* __restrict__ invdeg) {
    int lane = threadIdx.x & 31;
    int grp  = threadIdx.x >> 5;
    int n = blockIdx.x * 8 + grp;   // NN/8 = 1250 blocks exactly
    int b = blockIdx.y;
    int e0 = off[n], e1 = off[n + 1];
    const float* xb = xin + (size_t)b * NN * HH;
    float acc = 0.f;
    int e = e0;
    for (; e + 4 <= e1; e += 4) {
        int   s0 = idx[e],   s1 = idx[e+1], s2 = idx[e+2], s3 = idx[e+3];
        float w0 = w[e],     w1 = w[e+1],   w2 = w[e+2],   w3 = w[e+3];
        acc += w0 * xb[(size_t)s0*HH + lane];
        acc += w1 * xb[(size_t)s1*HH + lane];
        acc += w2 * xb[(size_t)s2*HH + lane];
        acc += w3 * xb[(size_t)s3*HH + lane];
    }
    for (; e < e1; ++e) acc += w[e] * xb[(size_t)idx[e]*HH + lane];
    yout[((size_t)b*NN + n)*HH + lane] = acc * invdeg[n];
}

// ---- acc[b,n,0:12] += piece[b,n,0:32] @ W2[c0:c0+32, 0:12]
__global__ __launch_bounds__(320) void k_accum(const float* __restrict__ piece,
                        const float* __restrict__ W2, float* __restrict__ acc, int c0) {
    int r = blockIdx.x * blockDim.x + threadIdx.x;  // 80000 exactly
    float a[12];
    float* ap = acc + (size_t)r * 12;
    #pragma unroll
    for (int o = 0; o < 12; o++) a[o] = ap[o];
    const float4* p4 = (const float4*)(piece + (size_t)r * HH);
    #pragma unroll
    for (int q = 0; q < 8; q++) {
        float4 v = p4[q];
        float pv[4] = {v.x, v.y, v.z, v.w};
        #pragma unroll
        for (int k = 0; k < 4; k++) {
            const float* wrow = W2 + (size_t)(c0 + 4*q + k) * 12;
            #pragma unroll
            for (int o = 0; o < 12; o++) a[o] += pv[k] * wrow[o];
        }
    }
    #pragma unroll
    for (int o = 0; o < 12; o++) ap[o] = a[o];
}

// ---- out[b,t,n,0] = acc[b,n,t] + b2[t]
__global__ __launch_bounds__(320) void k_out(const float* __restrict__ acc,
                     const float* __restrict__ b2, float* __restrict__ out) {
    int r = blockIdx.x * blockDim.x + threadIdx.x;  // 80000 exactly
    int b = r / NN, n = r % NN;
    const float* ap = acc + (size_t)r * 12;
    #pragma unroll
    for (int t = 0; t < HOR; t++)
        out[((size_t)(b*HOR + t))*NN + n] = ap[t] + b2[t];
}

extern "C" void kernel_launch(void* const* d_in, const int* in_sizes, int n_in,
                              void* d_out, int out_size, void* d_ws, size_t ws_size,
                              hipStream_t stream) {
    const float* x      = (const float*)d_in[0];
    const int*   ei     = (const int*)d_in[1];
    const float* ew     = (const float*)d_in[2];
    const float* enc_w  = (const float*)d_in[3];
    const float* enc_b  = (const float*)d_in[4];
    const float* nemb   = (const float*)d_in[5];
    const float* w_ih   = (const float*)d_in[6];
    const float* w_hh   = (const float*)d_in[7];
    const float* b_ih   = (const float*)d_in[8];
    const float* b_hh   = (const float*)d_in[9];
    const float* filt_w = (const float*)d_in[10];
    const float* filt_b = (const float*)d_in[11];
    const float* dec_w  = (const float*)d_in[12];
    const float* dec_b  = (const float*)d_in[13];
    float* out = (float*)d_out;

    char* p = (char*)d_ws;
    auto alloc = [&](size_t bytes) -> char* {
        char* q = p; p += (bytes + 255) & ~(size_t)255; return q;
    };
    // zero-region (single memset): acc, cnt_f, cnt_b, deg_f, deg_b
    char* zero_base = p;
    float* acc   = (float*)alloc((size_t)BB*NN*12*4);
    int*   cnt_f = (int*)  alloc((size_t)NN*4);
    int*   cnt_b = (int*)  alloc((size_t)NN*4);
    float* deg_f = (float*)alloc((size_t)NN*4);
    float* deg_b = (float*)alloc((size_t)NN*4);
    size_t zero_bytes = (size_t)(p - zero_base);

    float* h_time = (float*)alloc((size_t)BB*NN*HH*4);
    float* yA     = (float*)alloc((size_t)BB*NN*HH*4);
    float* yB     = (float*)alloc((size_t)BB*NN*HH*4);
    float* CB     = (float*)alloc((size_t)NN*96*4);
    float* A      = (float*)alloc(96*4);
    float* W2     = (float*)alloc(1920*4);
    float* b2     = (float*)alloc(12*4);
    float* inv_f  = (float*)alloc((size_t)NN*4);
    float* inv_b  = (float*)alloc((size_t)NN*4);
    int*   off_f  = (int*)  alloc((size_t)(NN+1)*4);
    int*   off_b  = (int*)  alloc((size_t)(NN+1)*4);
    int*   cur_f  = (int*)  alloc((size_t)NN*4);
    int*   cur_b  = (int*)  alloc((size_t)NN*4);
    int*   cfi    = (int*)  alloc((size_t)EE*4);
    float* cfw    = (float*)alloc((size_t)EE*4);
    int*   cbi    = (int*)  alloc((size_t)EE*4);
    float* cbw    = (float*)alloc((size_t)EE*4);

    hipMemsetAsync(zero_base, 0, zero_bytes, stream);

    k_prep<<<1, 256, 0, stream>>>(enc_w, w_ih, filt_w, filt_b, dec_w, dec_b, A, W2, b2);
    k_cb<<<NN*96/256, 256, 0, stream>>>(nemb, enc_b, w_ih, b_ih, CB);
    k_hist<<<EE/256, 256, 0, stream>>>(ei, ew, cnt_f, cnt_b, deg_f, deg_b);
    k_scan<<<2, 1024, 0, stream>>>(cnt_f, deg_f, off_f, cur_f, inv_f,
                                   cnt_b, deg_b, off_b, cur_b, inv_b);
    k_fill<<<EE/256, 256, 0, stream>>>(ei, ew, cur_f, cfi, cfw, cur_b, cbi, cbw);

    k_gru<<<BB*NN/320, 320, 0, stream>>>(x, CB, A, w_hh, b_hh, h_time);

    dim3 pgrid(NN/8, BB);
    k_accum<<<BB*NN/320, 320, 0, stream>>>(h_time, W2, acc, 0);
    k_prop<<<pgrid, 256, 0, stream>>>(h_time, yA, off_f, cfi, cfw, inv_f);
    k_accum<<<BB*NN/320, 320, 0, stream>>>(yA, W2, acc, 32);
    k_prop<<<pgrid, 256, 0, stream>>>(yA, yB, off_f, cfi, cfw, inv_f);
    k_accum<<<BB*NN/320, 320, 0, stream>>>(yB, W2, acc, 64);
    k_prop<<<pgrid, 256, 0, stream>>>(h_time, yA, off_b, cbi, cbw, inv_b);
    k_accum<<<BB*NN/320, 320, 0, stream>>>(yA, W2, acc, 96);
    k_prop<<<pgrid, 256, 0, stream>>>(yA, yB, off_b, cbi, cbw, inv_b);
    k_accum<<<BB*NN/320, 320, 0, stream>>>(yB, W2, acc, 128);

    k_out<<<BB*NN/320, 320, 0, stream>>>(acc, b2, out);
}